// Round 6
// baseline (439.246 us; speedup 1.0000x reference)
//
#include <hip/hip_runtime.h>
#include <math.h>

namespace {
constexpr int BB = 32, NPG = 4096, NTOT = BB*NPG, C = 128, FIN = 64, KK = 32, JJ = 40;
constexpr int YROWS = BB*JJ; // 1280
constexpr float EPS = 1e-5f;

// CW (precomputed folded constants) float offsets
constexpr int CW_WU  = 0;      // [64][32] Wu[d][k] = sum_c W[c][d]*U[c][k]
constexpr int CW_WV  = 2048;   // [64][32] Wv[d][k] = sum_c W[c][d]*V[c][k]
constexpr int CW_VU  = 4096;   // [32][32] VU[k'][k] = sum_c V[c][k']*U[c][k]
constexpr int CW_WG  = 5120;   // [64]     sum_c W[c][d]*gw[c]
constexpr int CW_VGX = 5184;   // [32]     sum_c V[c][k]*gw[c]
constexpr int CW_VGH = 5216;   // [32]     sum_c V[c][k]*gw[128+c]
constexpr int CW_CBU = 5248;   // [32]     sum_c b[c]*U[c][k]
constexpr int CW_CSU = 5280;   // [32]     sum_c U[c][k]
constexpr int CW_CBV = 5312;   // [32]     sum_c b[c]*V[c][k]
constexpr int CW_CSV = 5344;   // [32]     sum_c V[c][k]
constexpr int CW_SC  = 5376;   // bG = b.gw[0:128], sG = sum gw[0:128]
constexpr int CW_G   = 5384;   // [64][64] G[d][e] = sum_c W[c][d]*W[c][e]
constexpr int CW_WB  = 9480;   // [64]     wb[d] = sum_c W[c][d]*b[c]
constexpr int CW_SW  = 9544;   // [64]     sw[d] = sum_c W[c][d]
constexpr int CW_SB  = 9608;   // sb = sum b, sb2 = sum b^2
constexpr int CW_SIZE = 9610;

// workspace layout (float offsets), all fp32 except ST/PB (double)
constexpr size_t XU_OFF  = 0;                               // NTOT*32
constexpr size_t GX_OFF  = XU_OFF + (size_t)NTOT*KK;        // NTOT
constexpr size_t YP_OFF  = GX_OFF + (size_t)NTOT;           // 1280*32
constexpr size_t PMA_OFF = YP_OFF + (size_t)YROWS*KK;       // 32*40*64
constexpr size_t PSA_OFF = PMA_OFF + 81920;
constexpr size_t PMB_OFF = PSA_OFF + 81920;
constexpr size_t PSB_OFF = PMB_OFF + 81920;
constexpr size_t CWS_OFF = PSB_OFF + 81920;
constexpr size_t PBN_OFF = CWS_OFF + 9612;                  // 512 double-pairs (nf)
constexpr size_t PBF_OFF = PBN_OFF + 2048;                  // 20 double-pairs (fe)
constexpr size_t MS_OFF  = PBF_OFF + 80;                    // 32*80 (M,Si per graph)
constexpr size_t ST_OFF  = MS_OFF + 2560;                   // 4 doubles
}

#define ACC8(A, wv, u0, u1) do { \
  A[0] += (wv)*(u0).x; A[1] += (wv)*(u0).y; A[2] += (wv)*(u0).z; A[3] += (wv)*(u0).w; \
  A[4] += (wv)*(u1).x; A[5] += (wv)*(u1).y; A[6] += (wv)*(u1).z; A[7] += (wv)*(u1).w; } while(0)

__device__ __forceinline__ float dot4(const float4 a, const float4 b) {
  return a.x*b.x + a.y*b.y + a.z*b.z + a.w*b.w;
}
__device__ __forceinline__ float dot8v(const float x[8], const float4 y0, const float4 y1) {
  return x[0]*y0.x + x[1]*y0.y + x[2]*y0.z + x[3]*y0.w
       + x[4]*y1.x + x[5]*y1.y + x[6]*y1.z + x[7]*y1.w;
}
__device__ __forceinline__ float sigm(const float x) { return 1.f/(1.f + __expf(-x)); }

// ---------------------------------------------------------------------------
// K0: fold W/U/V/gate into small matrices. Block 0: WU/WV/VU/gate folds.
// Block 1: G = W^T W, wb, sw, sb/sb2.   (unchanged, proven)
// ---------------------------------------------------------------------------
__global__ __launch_bounds__(256)
void k_pre(const float* __restrict__ W, const float* __restrict__ b,
           const float* __restrict__ U, const float* __restrict__ V,
           const float* __restrict__ gw, float* __restrict__ CWo) {
  __shared__ float W_l[128*64];
  __shared__ float V_l[128*32];
  const int t = threadIdx.x;
  for (int f = t; f < 2048; f += 256) *(float4*)(W_l + 4*f) = *(const float4*)(W + 4*f);
  if (blockIdx.x == 0)
    for (int f = t; f < 1024; f += 256) *(float4*)(V_l + 4*f) = *(const float4*)(V + 4*f);
  __syncthreads();
  if (blockIdx.x == 1) {
    const int d = t >> 2, e0 = (t & 3) * 16;
    float g[16];
    #pragma unroll
    for (int i = 0; i < 16; ++i) g[i] = 0.f;
    for (int c = 0; c < 128; ++c) {
      const float wv = W_l[c*64 + d];
      #pragma unroll
      for (int u = 0; u < 4; ++u) {
        const float4 we = *(const float4*)(W_l + c*64 + e0 + 4*u);
        g[4*u+0] += wv*we.x; g[4*u+1] += wv*we.y;
        g[4*u+2] += wv*we.z; g[4*u+3] += wv*we.w;
      }
    }
    #pragma unroll
    for (int u = 0; u < 4; ++u)
      *(float4*)(CWo + CW_G + d*64 + e0 + 4*u) = make_float4(g[4*u],g[4*u+1],g[4*u+2],g[4*u+3]);
    if (t < 64) {
      float awb = 0.f, asw = 0.f;
      for (int c = 0; c < 128; ++c) {
        const float wv = W_l[c*64 + t];
        awb += wv * b[c]; asw += wv;
      }
      CWo[CW_WB + t] = awb; CWo[CW_SW + t] = asw;
    }
    if (t == 0) {
      float sb = 0.f, sb2 = 0.f;
      for (int c = 0; c < 128; ++c) { sb += b[c]; sb2 += b[c]*b[c]; }
      CWo[CW_SB+0] = sb; CWo[CW_SB+1] = sb2;
    }
    return;
  }
  {
    const int d = t >> 2, k0 = (t & 3) * 8;
    float au[8] = {0,0,0,0,0,0,0,0};
    float av[8] = {0,0,0,0,0,0,0,0};
    for (int c = 0; c < 128; ++c) {
      const float wv = W_l[c*64 + d];
      const float4 u0 = *(const float4*)(U + c*32 + k0);
      const float4 u1 = *(const float4*)(U + c*32 + k0 + 4);
      ACC8(au, wv, u0, u1);
      const float4 v0 = *(const float4*)(V_l + c*32 + k0);
      const float4 v1 = *(const float4*)(V_l + c*32 + k0 + 4);
      ACC8(av, wv, v0, v1);
    }
    *(float4*)(CWo + CW_WU + d*32 + k0)     = make_float4(au[0],au[1],au[2],au[3]);
    *(float4*)(CWo + CW_WU + d*32 + k0 + 4) = make_float4(au[4],au[5],au[6],au[7]);
    *(float4*)(CWo + CW_WV + d*32 + k0)     = make_float4(av[0],av[1],av[2],av[3]);
    *(float4*)(CWo + CW_WV + d*32 + k0 + 4) = make_float4(av[4],av[5],av[6],av[7]);
  }
  if (t < 128) {
    const int kp = t >> 2, k0 = (t & 3) * 8;
    float a[8] = {0,0,0,0,0,0,0,0};
    for (int c = 0; c < 128; ++c) {
      const float vv = V_l[c*32 + kp];
      const float4 u0 = *(const float4*)(U + c*32 + k0);
      const float4 u1 = *(const float4*)(U + c*32 + k0 + 4);
      ACC8(a, vv, u0, u1);
    }
    *(float4*)(CWo + CW_VU + kp*32 + k0)     = make_float4(a[0],a[1],a[2],a[3]);
    *(float4*)(CWo + CW_VU + kp*32 + k0 + 4) = make_float4(a[4],a[5],a[6],a[7]);
  }
  if (t < 64) {
    float a = 0.f;
    for (int c = 0; c < 128; ++c) a += W_l[c*64 + t] * gw[c];
    CWo[CW_WG + t] = a;
  }
  if (t < 32) {
    float a1=0,a2=0,a3=0,a4=0,a5=0,a6=0;
    for (int c = 0; c < 128; ++c) {
      const float uv = U[c*32 + t], vv = V_l[c*32 + t], bc = b[c];
      a1 += vv*gw[c]; a2 += vv*gw[128+c];
      a3 += bc*uv;    a4 += uv;
      a5 += bc*vv;    a6 += vv;
    }
    CWo[CW_VGX+t]=a1; CWo[CW_VGH+t]=a2; CWo[CW_CBU+t]=a3; CWo[CW_CSU+t]=a4;
    CWo[CW_CBV+t]=a5; CWo[CW_CSV+t]=a6;
  }
  if (t == 0) {
    float bg=0.f, sg=0.f;
    for (int c = 0; c < 128; ++c) { bg += b[c]*gw[c]; sg += gw[c]; }
    CWo[CW_SC+0]=bg; CWo[CW_SC+1]=sg;
  }
}

// ---------------------------------------------------------------------------
// K1: stats via second moments (unchanged, proven). Per-block pair to PB.
// ---------------------------------------------------------------------------
__global__ __launch_bounds__(256,6)
void k_cov(const float* __restrict__ inp, const float* __restrict__ CW,
           double* __restrict__ PB, const int ntiles) {
  __shared__ float a_l[64*64];
  __shared__ float red[12];
  const int t = threadIdx.x;
  const int dg = t >> 4, eg = t & 15;
  const int d0 = dg*4, e0 = eg*4;
  float av1 = 0.f, av2 = 0.f, avb = 0.f;
  int nt = 0;
  for (int tile = blockIdx.x; tile < ntiles; tile += gridDim.x) {
    __syncthreads();
    const size_t r0 = (size_t)tile * 64;
    #pragma unroll
    for (int s = 0; s < 4; ++s) {
      int f = (t + 256*s) * 4;
      *(float4*)(a_l + f) = *(const float4*)(inp + r0*FIN + f);
    }
    __syncthreads();
    float S[4][4];
    #pragma unroll
    for (int i=0;i<4;i++)
      #pragma unroll
      for (int j=0;j<4;j++) S[i][j] = 0.f;
    float4 cs = make_float4(0.f,0.f,0.f,0.f);
    #pragma unroll 4
    for (int r = 0; r < 64; ++r) {
      const float4 ad = *(const float4*)(a_l + r*64 + d0);
      const float4 ae = *(const float4*)(a_l + r*64 + e0);
      S[0][0]+=ad.x*ae.x; S[0][1]+=ad.x*ae.y; S[0][2]+=ad.x*ae.z; S[0][3]+=ad.x*ae.w;
      S[1][0]+=ad.y*ae.x; S[1][1]+=ad.y*ae.y; S[1][2]+=ad.y*ae.z; S[1][3]+=ad.y*ae.w;
      S[2][0]+=ad.z*ae.x; S[2][1]+=ad.z*ae.y; S[2][2]+=ad.z*ae.z; S[2][3]+=ad.z*ae.w;
      S[3][0]+=ad.w*ae.x; S[3][1]+=ad.w*ae.y; S[3][2]+=ad.w*ae.z; S[3][3]+=ad.w*ae.w;
      cs.x += ad.x; cs.y += ad.y; cs.z += ad.z; cs.w += ad.w;
    }
    #pragma unroll
    for (int i = 0; i < 4; ++i) {
      const float4 g4 = *(const float4*)(CW + CW_G + (d0+i)*64 + e0);
      av2 += S[i][0]*g4.x + S[i][1]*g4.y + S[i][2]*g4.z + S[i][3]*g4.w;
    }
    if (eg == 0) {
      const float4 sw4 = *(const float4*)(CW + CW_SW + d0);
      const float4 wb4 = *(const float4*)(CW + CW_WB + d0);
      av1 += cs.x*sw4.x + cs.y*sw4.y + cs.z*sw4.z + cs.w*sw4.w;
      avb += cs.x*wb4.x + cs.y*wb4.y + cs.z*wb4.z + cs.w*wb4.w;
    }
    ++nt;
  }
  #pragma unroll
  for (int off = 32; off > 0; off >>= 1) {
    av2 += __shfl_xor(av2, off);
    av1 += __shfl_xor(av1, off);
    avb += __shfl_xor(avb, off);
  }
  const int w = t >> 6;
  if ((t & 63) == 0) { red[w*3] = av1; red[w*3+1] = av2; red[w*3+2] = avb; }
  __syncthreads();
  if (t == 0) {
    const float sb = CW[CW_SB], sb2 = CW[CW_SB+1];
    const double rowsB = 64.0 * (double)nt;
    const double s1 = (double)(red[0]+red[3]+red[6]+red[9]);
    const double s2 = (double)(red[1]+red[4]+red[7]+red[10]);
    const double sB = (double)(red[2]+red[5]+red[8]+red[11]);
    PB[(size_t)blockIdx.x*2 + 0] = s1 + rowsB*(double)sb;
    PB[(size_t)blockIdx.x*2 + 1] = s2 + 2.0*sB + rowsB*(double)sb2;
  }
}

// ---------------------------------------------------------------------------
// K1b: combine per-block double-pairs into ST[0..3]. One block.
// ---------------------------------------------------------------------------
__global__ __launch_bounds__(256)
void k_comb(const double* __restrict__ PBn, const double* __restrict__ PBf,
            double* __restrict__ ST) {
  __shared__ double red[8];
  const int t = threadIdx.x;
  double a = PBn[2*t] + PBn[2*(t+256)];
  double b = PBn[2*t+1] + PBn[2*(t+256)+1];
  #pragma unroll
  for (int off = 32; off > 0; off >>= 1) {
    a += __shfl_down(a, off);
    b += __shfl_down(b, off);
  }
  if ((t & 63) == 0) { red[(t>>6)*2] = a; red[(t>>6)*2+1] = b; }
  __syncthreads();
  if (t == 0) {
    ST[0] = red[0]+red[2]+red[4]+red[6];
    ST[1] = red[1]+red[3]+red[5]+red[7];
  }
  if (t < 64) {
    double c = (t < 20) ? PBf[2*t]   : 0.0;
    double d = (t < 20) ? PBf[2*t+1] : 0.0;
    #pragma unroll
    for (int off = 32; off > 0; off >>= 1) {
      c += __shfl_down(c, off);
      d += __shfl_down(d, off);
    }
    if (t == 0) { ST[2] = c; ST[3] = d; }
  }
}

// ---------------------------------------------------------------------------
// K1c: combine softmax partials (Pm/Ps 64-wide) into per-(b,j) M, 1/S.
// grid = 32 (one block per graph).
// ---------------------------------------------------------------------------
__global__ __launch_bounds__(256)
void k_comb2(const float* __restrict__ Pm, const float* __restrict__ Ps,
             float* __restrict__ MS) {
  __shared__ float Mq[160], Sq[160], Msh[40];
  const int t = threadIdx.x;
  const int b = blockIdx.x;
  const int j = t >> 2, q = t & 3;
  float pm[16];
  if (t < 160) {
    float m = 0.f;
    #pragma unroll
    for (int u = 0; u < 16; ++u) {
      pm[u] = Pm[(size_t)b*2560 + j*64 + q*16 + u];
      m = fmaxf(m, pm[u]);
    }
    Mq[t] = m;
  }
  __syncthreads();
  if (t < 40) Msh[t] = fmaxf(fmaxf(Mq[4*t], Mq[4*t+1]), fmaxf(Mq[4*t+2], Mq[4*t+3]));
  __syncthreads();
  if (t < 160) {
    const float M = Msh[j];
    float s = 0.f;
    #pragma unroll
    for (int u = 0; u < 16; ++u)
      s += Ps[(size_t)b*2560 + j*64 + q*16 + u] * __expf(pm[u] - M);
    Sq[t] = s;
  }
  __syncthreads();
  if (t < 40) {
    const float S = Sq[4*t] + Sq[4*t+1] + Sq[4*t+2] + Sq[4*t+3];
    MS[(size_t)b*80 + t] = Msh[t];
    MS[(size_t)b*80 + 40 + t] = 1.f/S;
  }
}

// ---------------------------------------------------------------------------
// irow4: 4 rows per thread. kq = t&3 (8-k slice), jh = (t>>2)&3 (10-j slice).
// p[i][jj] = full-k dot after xor1,2 (DPP) reduce. ypj stride 40.
// ---------------------------------------------------------------------------
__device__ __forceinline__ void irow4(const float* ypj, const int kq, const int jh,
                                      const float xp[4][8], float p[4][10]) {
  #pragma unroll
  for (int jj = 0; jj < 10; ++jj) {
    const int j = jh*10 + jj;
    const float4 y0 = *(const float4*)(ypj + j*40 + kq*8);
    const float4 y1 = *(const float4*)(ypj + j*40 + kq*8 + 4);
    #pragma unroll
    for (int i = 0; i < 4; ++i)
      p[i][jj] = dot8v(xp[i], y0, y1);
  }
  #pragma unroll
  for (int i = 0; i < 4; ++i)
    #pragma unroll
    for (int jj = 0; jj < 10; ++jj) {
      p[i][jj] += __shfl_xor(p[i][jj], 1);
      p[i][jj] += __shfl_xor(p[i][jj], 2);
    }
}

// ---------------------------------------------------------------------------
// partials_lds: softmax partials from p staged in LDS (stride 44). Proven.
// ---------------------------------------------------------------------------
__device__ __forceinline__ void partials_lds(const float* p_l, const int t,
    float* sredm, float* sreds, float* redm,
    float* __restrict__ PmB, float* __restrict__ PsB) {
  const int r2 = t >> 2, kq = t & 3;
  const int w = t >> 6, tl = t & 63;
  float ev[10];
  #pragma unroll
  for (int m = 0; m < 10; ++m) ev[m] = p_l[r2*44 + 4*m + kq];
  float mv[10];
  #pragma unroll
  for (int m = 0; m < 10; ++m) {
    mv[m] = ev[m];
    mv[m] = fmaxf(mv[m], __shfl_xor(mv[m], 4));
    mv[m] = fmaxf(mv[m], __shfl_xor(mv[m], 8));
    mv[m] = fmaxf(mv[m], __shfl_xor(mv[m], 16));
    mv[m] = fmaxf(mv[m], __shfl_xor(mv[m], 32));
  }
  if (tl < 4) {
    #pragma unroll
    for (int m = 0; m < 10; ++m) sredm[w*40 + 4*m + kq] = mv[m];
  }
  __syncthreads();
  if (t < 40)
    redm[t] = fmaxf(fmaxf(sredm[t], sredm[40+t]), fmaxf(sredm[80+t], sredm[120+t]));
  __syncthreads();
  float es[10];
  #pragma unroll
  for (int m = 0; m < 10; ++m) {
    const float M = redm[4*m + kq];
    es[m] = __expf(ev[m]-M);
    es[m] += __shfl_xor(es[m], 4);
    es[m] += __shfl_xor(es[m], 8);
    es[m] += __shfl_xor(es[m], 16);
    es[m] += __shfl_xor(es[m], 32);
  }
  if (tl < 4) {
    #pragma unroll
    for (int m = 0; m < 10; ++m) sreds[w*40 + 4*m + kq] = es[m];
  }
  __syncthreads();
  if (t < 40) {
    PmB[(size_t)t*64] = redm[t];
    PsB[(size_t)t*64] = sreds[t]+sreds[40+t]+sreds[80+t]+sreds[120+t];
  }
}

// ---------------------------------------------------------------------------
// K2: y_p directly from fe (unchanged, proven).
// ---------------------------------------------------------------------------
__global__ __launch_bounds__(256,4)
void k_yp2(const float* __restrict__ fe, const float* __restrict__ CW,
           const float* __restrict__ q, const double* __restrict__ ST,
           float* __restrict__ yp) {
  __shared__ float in_t[64*64];
  __shared__ float Wl[64*32];
  const int t = threadIdx.x;
  const int r0 = blockIdx.x * 64;
  #pragma unroll
  for (int s = 0; s < 4; ++s) {
    int f = (t + 256*s) * 4;
    int r = f >> 6, d = f & 63;
    float4 v = *(const float4*)(fe + (size_t)r0*FIN + f);
    *(float4*)(in_t + r*64 + (d ^ ((r & 7) * 8))) = v;
  }
  #pragma unroll
  for (int s = 0; s < 2; ++s) {
    int f = (t + 256*s) * 4;
    *(float4*)(Wl + f) = *(const float4*)(CW + CW_WV + f);
  }
  __syncthreads();
  const double cy = (double)YROWS * (double)C;
  const double myd = ST[2]/cy, vy = ST[3]/cy - myd*myd;
  const float ry = (float)(1.0/sqrt(vy + (double)EPS));
  const float mr = (float)myd * ry;
  const int r2 = t >> 2, kq = t & 3;
  const int swz = (r2 & 7) * 8;
  float acc[8] = {0,0,0,0,0,0,0,0};
  #pragma unroll
  for (int dc = 0; dc < 16; ++dc) {
    const int d = dc*4;
    const float4 a = *(const float4*)(in_t + r2*64 + (d ^ swz));
    { const float4 w0 = *(const float4*)(Wl + (d+0)*32 + kq*8);
      const float4 w1 = *(const float4*)(Wl + (d+0)*32 + kq*8 + 4); ACC8(acc, a.x, w0, w1); }
    { const float4 w0 = *(const float4*)(Wl + (d+1)*32 + kq*8);
      const float4 w1 = *(const float4*)(Wl + (d+1)*32 + kq*8 + 4); ACC8(acc, a.y, w0, w1); }
    { const float4 w0 = *(const float4*)(Wl + (d+2)*32 + kq*8);
      const float4 w1 = *(const float4*)(Wl + (d+2)*32 + kq*8 + 4); ACC8(acc, a.z, w0, w1); }
    { const float4 w0 = *(const float4*)(Wl + (d+3)*32 + kq*8);
      const float4 w1 = *(const float4*)(Wl + (d+3)*32 + kq*8 + 4); ACC8(acc, a.w, w0, w1); }
  }
  #pragma unroll
  for (int i = 0; i < 8; ++i) {
    const int k = kq*8 + i;
    const float typ = ry*(acc[i] + CW[CW_CBV+k]) - mr*CW[CW_CSV+k];
    float v = fmaxf(typ, 0.f);
    acc[i] = fmaxf(q[k]*v, 0.f);
  }
  *(float4*)(yp + (size_t)(r0+r2)*KK + kq*8)     = make_float4(acc[0],acc[1],acc[2],acc[3]);
  *(float4*)(yp + (size_t)(r0+r2)*KK + kq*8 + 4) = make_float4(acc[4],acc[5],acc[6],acc[7]);
}

// ---------------------------------------------------------------------------
// K3: layer-0, 4-row register-blocked. GEMM: contraction d split over X lanes
// (xor4,8 reduce); irow4 + partials. ypj stride 40; Wl row-swizzled stride 36.
// ---------------------------------------------------------------------------
__global__ __launch_bounds__(256,4)
void k_I0b(const float* __restrict__ nf, const float* __restrict__ CW,
           const double* __restrict__ ST, const float* __restrict__ yp,
           float* __restrict__ XU, float* __restrict__ GX,
           float* __restrict__ Pm, float* __restrict__ Ps) {
  __shared__ __align__(16) float in_t[64*68];   // overlaid by p_l (64*44) later
  __shared__ __align__(16) float Wl[64*36];     // row d -> (d&15)*4 + (d>>4)
  __shared__ __align__(16) float ypj[40*40];
  __shared__ __align__(16) float wgl[64];
  __shared__ float sredm[160], sreds[160], redm[40];
  float* p_l = in_t;
  const int t = threadIdx.x;
  const int bid = blockIdx.x;
  const int b = bid >> 6, blk = bid & 63;
  const size_t rowbase = (size_t)b*NPG + (size_t)blk*64;
  #pragma unroll
  for (int s = 0; s < 4; ++s) {
    int f = (t + 256*s) * 4;
    int r = f >> 6, d = f & 63;
    *(float4*)(in_t + r*68 + d) = *(const float4*)(nf + rowbase*FIN + f);
  }
  #pragma unroll
  for (int s = 0; s < 2; ++s) {
    int idx = t + 256*s;
    int d = idx >> 3, kc = idx & 7;
    *(float4*)(Wl + ((d&15)*4 + (d>>4))*36 + kc*4) = *(const float4*)(CW + CW_WU + idx*4);
  }
  for (int f4v = t; f4v < 320; f4v += 256) {
    int j = f4v >> 3, kc = f4v & 7;
    *(float4*)(ypj + j*40 + kc*4) = *(const float4*)(yp + (size_t)b*(JJ*KK) + f4v*4);
  }
  if (t < 64) wgl[t] = CW[CW_WG + t];
  __syncthreads();
  const double cx = (double)NTOT * (double)C;
  const double mx = ST[0]/cx, vx = ST[1]/cx - mx*mx;
  const float rx = (float)(1.0/sqrt(vx + (double)EPS));
  const float mr = (float)mx * rx;
  const int kq = t & 3, X = (t >> 2) & 3, rr = t >> 4;
  float acc[4][8];
  #pragma unroll
  for (int i=0;i<4;i++)
    #pragma unroll
    for (int u=0;u<8;u++) acc[i][u] = 0.f;
  #pragma unroll
  for (int dd = 0; dd < 4; ++dd) {
    float4 a4[4];
    #pragma unroll
    for (int i = 0; i < 4; ++i)
      a4[i] = *(const float4*)(in_t + (rr+16*i)*68 + X*16 + dd*4);
    #pragma unroll
    for (int qd = 0; qd < 4; ++qd) {
      const int lrow = (dd*4 + qd)*4 + X;
      const float4 w0 = *(const float4*)(Wl + lrow*36 + kq*8);
      const float4 w1 = *(const float4*)(Wl + lrow*36 + kq*8 + 4);
      #pragma unroll
      for (int i = 0; i < 4; ++i) {
        const float av = (qd==0)? a4[i].x : (qd==1)? a4[i].y : (qd==2)? a4[i].z : a4[i].w;
        ACC8(acc[i], av, w0, w1);
      }
    }
  }
  // X-reduce (full 64-d sum)
  #pragma unroll
  for (int i = 0; i < 4; ++i)
    #pragma unroll
    for (int u = 0; u < 8; ++u) {
      acc[i][u] += __shfl_xor(acc[i][u], 4);
      acc[i][u] += __shfl_xor(acc[i][u], 8);
    }
  // gx: d-slice (X*16 + kq*4), reduce over 16 lanes
  float gp[4];
  #pragma unroll
  for (int i = 0; i < 4; ++i) {
    const float4 a = *(const float4*)(in_t + (rr+16*i)*68 + X*16 + kq*4);
    const float4 w = *(const float4*)(wgl + X*16 + kq*4);
    gp[i] = dot4(a, w);
    gp[i] += __shfl_xor(gp[i], 1);
    gp[i] += __shfl_xor(gp[i], 2);
    gp[i] += __shfl_xor(gp[i], 4);
    gp[i] += __shfl_xor(gp[i], 8);
  }
  const float4 cb0 = *(const float4*)(CW + CW_CBU + kq*8);
  const float4 cb1 = *(const float4*)(CW + CW_CBU + kq*8 + 4);
  const float4 cu0 = *(const float4*)(CW + CW_CSU + kq*8);
  const float4 cu1 = *(const float4*)(CW + CW_CSU + kq*8 + 4);
  float xp[4][8];
  #pragma unroll
  for (int i = 0; i < 4; ++i) {
    acc[i][0] = rx*(acc[i][0] + cb0.x) - mr*cu0.x;
    acc[i][1] = rx*(acc[i][1] + cb0.y) - mr*cu0.y;
    acc[i][2] = rx*(acc[i][2] + cb0.z) - mr*cu0.z;
    acc[i][3] = rx*(acc[i][3] + cb0.w) - mr*cu0.w;
    acc[i][4] = rx*(acc[i][4] + cb1.x) - mr*cu1.x;
    acc[i][5] = rx*(acc[i][5] + cb1.y) - mr*cu1.y;
    acc[i][6] = rx*(acc[i][6] + cb1.z) - mr*cu1.z;
    acc[i][7] = rx*(acc[i][7] + cb1.w) - mr*cu1.w;
    #pragma unroll
    for (int u = 0; u < 8; ++u) xp[i][u] = fmaxf(acc[i][u], 0.f);
  }
  if (X == 0) {
    const float bG = CW[CW_SC], sG = CW[CW_SC+1];
    #pragma unroll
    for (int i = 0; i < 4; ++i) {
      const size_t row = rowbase + rr + 16*i;
      *(float4*)(XU + row*KK + kq*8)     = make_float4(acc[i][0],acc[i][1],acc[i][2],acc[i][3]);
      *(float4*)(XU + row*KK + kq*8 + 4) = make_float4(acc[i][4],acc[i][5],acc[i][6],acc[i][7]);
      if (kq == 0) GX[row] = rx*(gp[i] + bG) - mr*sG;
    }
  }
  float p[4][10];
  irow4(ypj, kq, X, xp, p);
  __syncthreads();                       // all in_t reads done; overlay p_l
  if (kq == 0) {
    #pragma unroll
    for (int i = 0; i < 4; ++i)
      #pragma unroll
      for (int u = 0; u < 5; ++u)
        *(float2*)(p_l + (rr+16*i)*44 + X*10 + 2*u) = make_float2(p[i][2*u], p[i][2*u+1]);
  }
  __syncthreads();
  partials_lds(p_l, t, sredm, sreds, redm,
               Pm + (size_t)b*2560 + blk, Ps + (size_t)b*2560 + blk);
}

// ---------------------------------------------------------------------------
// K4: fused layer update, 4-row register-blocked.
// irow1 -> e (regs) -> h j-partials in regs + xor4/8 reduce -> h_l ->
// C: hu = h@VU + gate + blend (2-k per lane) -> xp_l -> irow3 -> partials/out.
// ---------------------------------------------------------------------------
template<int FINAL>
__global__ __launch_bounds__(256,4)
void k_fused3(float* __restrict__ XU, float* __restrict__ GX,
              const float* __restrict__ yp, const float* __restrict__ CW,
              const float* __restrict__ gb, const float* __restrict__ MS,
              float* __restrict__ PmOut, float* __restrict__ PsOut,
              float* __restrict__ outp) {
  __shared__ __align__(16) float ypj[40*40];
  __shared__ __align__(16) float xp_l[64*36];
  __shared__ __align__(16) float BUF[3456];   // h_l[64*36] | VU_l[32*36]; later p_l[64*44]
  __shared__ __align__(16) float vg_l[64];    // vgx[0:32], vgh[32:64]
  __shared__ float M_l[40], Si_l[40];
  __shared__ float sredm[160], sreds[160], redm[40];
  float* h_l  = BUF;
  float* VU_l = BUF + 2304;
  float* p_l  = BUF;
  const int t = threadIdx.x;
  const int bid = blockIdx.x;
  const int b = bid >> 6, blk = bid & 63;
  const size_t rowbase = (size_t)b*NPG + (size_t)blk*64;
  for (int f4v = t; f4v < 320; f4v += 256) {
    int j = f4v >> 3, kc = f4v & 7;
    *(float4*)(ypj + j*40 + kc*4) = *(const float4*)(yp + (size_t)b*(JJ*KK) + f4v*4);
  }
  { // VU (original orientation [kp][k]) stride 36
    const int d = t >> 3, kc = t & 7;
    *(float4*)(VU_l + d*36 + kc*4) = *(const float4*)(CW + CW_VU + t*4);
  }
  if (t < 32) vg_l[t] = CW[CW_VGX + t];
  else if (t < 64) vg_l[t] = CW[CW_VGH + t - 32];
  if (t < 40) { M_l[t] = MS[(size_t)b*80 + t]; Si_l[t] = MS[(size_t)b*80 + 40 + t]; }
  __syncthreads();
  const int kq = t & 3, jh = (t >> 2) & 3, rr = t >> 4;
  // load state, xp
  float xp[4][8];
  #pragma unroll
  for (int i = 0; i < 4; ++i) {
    const size_t row = rowbase + rr + 16*i;
    const float4 x0 = *(const float4*)(XU + row*KK + kq*8);
    const float4 x1 = *(const float4*)(XU + row*KK + kq*8 + 4);
    xp[i][0]=fmaxf(x0.x,0.f); xp[i][1]=fmaxf(x0.y,0.f);
    xp[i][2]=fmaxf(x0.z,0.f); xp[i][3]=fmaxf(x0.w,0.f);
    xp[i][4]=fmaxf(x1.x,0.f); xp[i][5]=fmaxf(x1.y,0.f);
    xp[i][6]=fmaxf(x1.z,0.f); xp[i][7]=fmaxf(x1.w,0.f);
  }
  // irow1 (recompute I, bitwise == partials producer)
  float p[4][10];
  irow4(ypj, kq, jh, xp, p);
  // e in regs + h j-partials
  float hp[4][8];
  #pragma unroll
  for (int i=0;i<4;i++)
    #pragma unroll
    for (int u=0;u<8;u++) hp[i][u] = 0.f;
  #pragma unroll
  for (int jj = 0; jj < 10; ++jj) {
    const int j = jh*10 + jj;
    const float Mj = M_l[j], Sj = Si_l[j];
    const float4 y0 = *(const float4*)(ypj + j*40 + kq*8);
    const float4 y1 = *(const float4*)(ypj + j*40 + kq*8 + 4);
    #pragma unroll
    for (int i = 0; i < 4; ++i) {
      const float e = __expf(p[i][jj] - Mj) * Sj;
      ACC8(hp[i], e, y0, y1);
    }
  }
  // jh-reduce -> full j sum
  #pragma unroll
  for (int i = 0; i < 4; ++i)
    #pragma unroll
    for (int u = 0; u < 8; ++u) {
      hp[i][u] += __shfl_xor(hp[i][u], 4);
      hp[i][u] += __shfl_xor(hp[i][u], 8);
    }
  if (jh == 0) {
    #pragma unroll
    for (int i = 0; i < 4; ++i) {
      const int rl = rr + 16*i;
      *(float4*)(h_l + rl*36 + kq*8) =
        make_float4(fmaxf(hp[i][0],0.f), fmaxf(hp[i][1],0.f),
                    fmaxf(hp[i][2],0.f), fmaxf(hp[i][3],0.f));
      *(float4*)(h_l + rl*36 + kq*8 + 4) =
        make_float4(fmaxf(hp[i][4],0.f), fmaxf(hp[i][5],0.f),
                    fmaxf(hp[i][6],0.f), fmaxf(hp[i][7],0.f));
    }
  }
  __syncthreads();
  // phase C: 2 output k per lane, full kp contraction, gate + blend
  {
    const int kk2 = t & 15, rr2 = t >> 4;
    float hu0[4] = {0,0,0,0}, hu1[4] = {0,0,0,0};
    float g2[4] = {0,0,0,0}, gxp[4] = {0,0,0,0};
    #pragma unroll
    for (int c8 = 0; c8 < 8; ++c8) {
      const float4 vgx4 = *(const float4*)(vg_l + c8*4);
      const float4 vgh4 = *(const float4*)(vg_l + 32 + c8*4);
      float2 vu[4];
      #pragma unroll
      for (int qd = 0; qd < 4; ++qd)
        vu[qd] = *(const float2*)(VU_l + (c8*4+qd)*36 + kk2*2);
      #pragma unroll
      for (int i = 0; i < 4; ++i) {
        const float4 h4 = *(const float4*)(h_l + (rr2+16*i)*36 + c8*4);
        g2[i]  += dot4(h4, vgh4);
        gxp[i] += dot4(h4, vgx4);
        hu0[i] += h4.x*vu[0].x + h4.y*vu[1].x + h4.z*vu[2].x + h4.w*vu[3].x;
        hu1[i] += h4.x*vu[0].y + h4.y*vu[1].y + h4.z*vu[2].y + h4.w*vu[3].y;
      }
    }
    const float gbv = gb[0];
    #pragma unroll
    for (int i = 0; i < 4; ++i) {
      const size_t row = rowbase + rr2 + 16*i;
      const float gx = GX[row];
      const float2 xu2 = *(const float2*)(XU + row*KK + kk2*2);
      const float z = sigm(gx + g2[i] + gbv);
      const float nx0 = (1.f-z)*xu2.x + z*hu0[i];
      const float nx1 = (1.f-z)*xu2.y + z*hu1[i];
      if (!FINAL) {
        *(float2*)(XU + row*KK + kk2*2) = make_float2(nx0, nx1);
        if (kk2 == 0) GX[row] = (1.f-z)*gx + z*gxp[i];
      }
      *(float2*)(xp_l + (rr2+16*i)*36 + kk2*2) = make_float2(fmaxf(nx0,0.f), fmaxf(nx1,0.f));
    }
  }
  __syncthreads();
  // irow3 on updated xp
  #pragma unroll
  for (int i = 0; i < 4; ++i) {
    const int rl = rr + 16*i;
    const float4 x0 = *(const float4*)(xp_l + rl*36 + kq*8);
    const float4 x1 = *(const float4*)(xp_l + rl*36 + kq*8 + 4);
    xp[i][0]=x0.x; xp[i][1]=x0.y; xp[i][2]=x0.z; xp[i][3]=x0.w;
    xp[i][4]=x1.x; xp[i][5]=x1.y; xp[i][6]=x1.z; xp[i][7]=x1.w;
  }
  irow4(ypj, kq, jh, xp, p);
  if (FINAL) {
    float s[4];
    #pragma unroll
    for (int i = 0; i < 4; ++i) {
      s[i] = 0.f;
      #pragma unroll
      for (int jj = 0; jj < 10; ++jj) s[i] += p[i][jj]*p[i][jj];
      s[i] += __shfl_xor(s[i], 4);
      s[i] += __shfl_xor(s[i], 8);
    }
    if ((t & 15) == 0) {
      #pragma unroll
      for (int i = 0; i < 4; ++i)
        outp[rowbase + rr + 16*i] = sigm(s[i]);
    }
    return;
  }
  if (kq == 0) {
    #pragma unroll
    for (int i = 0; i < 4; ++i)
      #pragma unroll
      for (int u = 0; u < 5; ++u)
        *(float2*)(p_l + (rr+16*i)*44 + jh*10 + 2*u) = make_float2(p[i][2*u], p[i][2*u+1]);
  }
  __syncthreads();
  partials_lds(p_l, t, sredm, sreds, redm,
               PmOut + (size_t)b*2560 + blk, PsOut + (size_t)b*2560 + blk);
}

extern "C" void kernel_launch(void* const* d_in, const int* in_sizes, int n_in,
                              void* d_out, int out_size, void* d_ws, size_t ws_size,
                              hipStream_t stream) {
  const float* nf  = (const float*)d_in[0];
  const float* fe  = (const float*)d_in[1];
  const float* W   = (const float*)d_in[2];
  const float* bin = (const float*)d_in[3];
  const float* U   = (const float*)d_in[4];
  const float* V   = (const float*)d_in[5];
  const float* q   = (const float*)d_in[6];
  const float* gw  = (const float*)d_in[7];
  const float* gb  = (const float*)d_in[8];
  float* out = (float*)d_out;
  float* wf  = (float*)d_ws;

  float* XU  = wf + XU_OFF;
  float* GX  = wf + GX_OFF;
  float* YP  = wf + YP_OFF;
  float* PMa = wf + PMA_OFF;
  float* PSa = wf + PSA_OFF;
  float* PMb = wf + PMB_OFF;
  float* PSb = wf + PSB_OFF;
  float* CWp = wf + CWS_OFF;
  float* MSb = wf + MS_OFF;
  double* PBn = (double*)(wf + PBN_OFF);
  double* PBf = (double*)(wf + PBF_OFF);
  double* ST  = (double*)(wf + ST_OFF);

  k_pre<<<2, 256, 0, stream>>>(W, bin, U, V, gw, CWp);
  k_cov<<<512, 256, 0, stream>>>(nf, CWp, PBn, NTOT/64);
  k_cov<<<20, 256, 0, stream>>>(fe, CWp, PBf, YROWS/64);
  k_comb<<<1, 256, 0, stream>>>(PBn, PBf, ST);
  k_yp2<<<YROWS/64, 256, 0, stream>>>(fe, CWp, q, ST, YP);
  k_I0b<<<NTOT/64, 256, 0, stream>>>(nf, CWp, ST, YP, XU, GX, PMa, PSa);
  k_comb2<<<32, 256, 0, stream>>>(PMa, PSa, MSb);
  k_fused3<0><<<NTOT/64, 256, 0, stream>>>(XU, GX, YP, CWp, gb, MSb, PMb, PSb, nullptr);
  k_comb2<<<32, 256, 0, stream>>>(PMb, PSb, MSb);
  k_fused3<1><<<NTOT/64, 256, 0, stream>>>(XU, GX, YP, CWp, gb, MSb, nullptr, nullptr, out);
}

// Round 7
// 334.489 us; speedup vs baseline: 1.3132x; 1.3132x over previous
//
#include <hip/hip_runtime.h>
#include <math.h>

namespace {
constexpr int BB = 32, NPG = 4096, NTOT = BB*NPG, C = 128, FIN = 64, KK = 32, JJ = 40;
constexpr int YROWS = BB*JJ; // 1280
constexpr float EPS = 1e-5f;

// CW (precomputed folded constants) float offsets
constexpr int CW_WU  = 0;      // [64][32] Wu[d][k] = sum_c W[c][d]*U[c][k]
constexpr int CW_WV  = 2048;   // [64][32] Wv[d][k] = sum_c W[c][d]*V[c][k]
constexpr int CW_VU  = 4096;   // [32][32] VU[k'][k] = sum_c V[c][k']*U[c][k]
constexpr int CW_WG  = 5120;   // [64]     sum_c W[c][d]*gw[c]
constexpr int CW_VGX = 5184;   // [32]     sum_c V[c][k]*gw[c]
constexpr int CW_VGH = 5216;   // [32]     sum_c V[c][k]*gw[128+c]
constexpr int CW_CBU = 5248;   // [32]     sum_c b[c]*U[c][k]
constexpr int CW_CSU = 5280;   // [32]     sum_c U[c][k]
constexpr int CW_CBV = 5312;   // [32]     sum_c b[c]*V[c][k]
constexpr int CW_CSV = 5344;   // [32]     sum_c V[c][k]
constexpr int CW_SC  = 5376;   // bG = b.gw[0:128], sG = sum gw[0:128]
constexpr int CW_G   = 5384;   // [64][64] G[d][e] = sum_c W[c][d]*W[c][e]
constexpr int CW_WB  = 9480;   // [64]     wb[d] = sum_c W[c][d]*b[c]
constexpr int CW_SW  = 9544;   // [64]     sw[d] = sum_c W[c][d]
constexpr int CW_SB  = 9608;   // sb = sum b, sb2 = sum b^2
constexpr int CW_SIZE = 9610;

// workspace layout (float offsets), all fp32 except ST/PB (double)
constexpr size_t XU_OFF  = 0;                               // NTOT*32
constexpr size_t GX_OFF  = XU_OFF + (size_t)NTOT*KK;        // NTOT
constexpr size_t YP_OFF  = GX_OFF + (size_t)NTOT;           // 1280*32
constexpr size_t PMA_OFF = YP_OFF + (size_t)YROWS*KK;       // 32*40*64
constexpr size_t PSA_OFF = PMA_OFF + 81920;
constexpr size_t PMB_OFF = PSA_OFF + 81920;
constexpr size_t PSB_OFF = PMB_OFF + 81920;
constexpr size_t CWS_OFF = PSB_OFF + 81920;
constexpr size_t PBN_OFF = CWS_OFF + 9612;                  // 512 double-pairs (nf)
constexpr size_t PBF_OFF = PBN_OFF + 2048;                  // 20 double-pairs (fe)
constexpr size_t MS_OFF  = PBF_OFF + 80;                    // 32*80 (M,Si per graph)
constexpr size_t ST_OFF  = MS_OFF + 2560;                   // 4 doubles
}

#define ACC8(A, wv, u0, u1) do { \
  A[0] += (wv)*(u0).x; A[1] += (wv)*(u0).y; A[2] += (wv)*(u0).z; A[3] += (wv)*(u0).w; \
  A[4] += (wv)*(u1).x; A[5] += (wv)*(u1).y; A[6] += (wv)*(u1).z; A[7] += (wv)*(u1).w; } while(0)

__device__ __forceinline__ float dot4(const float4 a, const float4 b) {
  return a.x*b.x + a.y*b.y + a.z*b.z + a.w*b.w;
}
__device__ __forceinline__ float dot8v(const float x[8], const float4 y0, const float4 y1) {
  return x[0]*y0.x + x[1]*y0.y + x[2]*y0.z + x[3]*y0.w
       + x[4]*y1.x + x[5]*y1.y + x[6]*y1.z + x[7]*y1.w;
}
__device__ __forceinline__ float sigm(const float x) { return 1.f/(1.f + __expf(-x)); }

// ---------------------------------------------------------------------------
// K0: fold W/U/V/gate into small matrices. Block 0: WU/WV/VU/gate folds.
// Block 1: G = W^T W, wb, sw, sb/sb2.   (unchanged, proven)
// ---------------------------------------------------------------------------
__global__ __launch_bounds__(256)
void k_pre(const float* __restrict__ W, const float* __restrict__ b,
           const float* __restrict__ U, const float* __restrict__ V,
           const float* __restrict__ gw, float* __restrict__ CWo) {
  __shared__ float W_l[128*64];
  __shared__ float V_l[128*32];
  const int t = threadIdx.x;
  for (int f = t; f < 2048; f += 256) *(float4*)(W_l + 4*f) = *(const float4*)(W + 4*f);
  if (blockIdx.x == 0)
    for (int f = t; f < 1024; f += 256) *(float4*)(V_l + 4*f) = *(const float4*)(V + 4*f);
  __syncthreads();
  if (blockIdx.x == 1) {
    const int d = t >> 2, e0 = (t & 3) * 16;
    float g[16];
    #pragma unroll
    for (int i = 0; i < 16; ++i) g[i] = 0.f;
    for (int c = 0; c < 128; ++c) {
      const float wv = W_l[c*64 + d];
      #pragma unroll
      for (int u = 0; u < 4; ++u) {
        const float4 we = *(const float4*)(W_l + c*64 + e0 + 4*u);
        g[4*u+0] += wv*we.x; g[4*u+1] += wv*we.y;
        g[4*u+2] += wv*we.z; g[4*u+3] += wv*we.w;
      }
    }
    #pragma unroll
    for (int u = 0; u < 4; ++u)
      *(float4*)(CWo + CW_G + d*64 + e0 + 4*u) = make_float4(g[4*u],g[4*u+1],g[4*u+2],g[4*u+3]);
    if (t < 64) {
      float awb = 0.f, asw = 0.f;
      for (int c = 0; c < 128; ++c) {
        const float wv = W_l[c*64 + t];
        awb += wv * b[c]; asw += wv;
      }
      CWo[CW_WB + t] = awb; CWo[CW_SW + t] = asw;
    }
    if (t == 0) {
      float sb = 0.f, sb2 = 0.f;
      for (int c = 0; c < 128; ++c) { sb += b[c]; sb2 += b[c]*b[c]; }
      CWo[CW_SB+0] = sb; CWo[CW_SB+1] = sb2;
    }
    return;
  }
  {
    const int d = t >> 2, k0 = (t & 3) * 8;
    float au[8] = {0,0,0,0,0,0,0,0};
    float av[8] = {0,0,0,0,0,0,0,0};
    for (int c = 0; c < 128; ++c) {
      const float wv = W_l[c*64 + d];
      const float4 u0 = *(const float4*)(U + c*32 + k0);
      const float4 u1 = *(const float4*)(U + c*32 + k0 + 4);
      ACC8(au, wv, u0, u1);
      const float4 v0 = *(const float4*)(V_l + c*32 + k0);
      const float4 v1 = *(const float4*)(V_l + c*32 + k0 + 4);
      ACC8(av, wv, v0, v1);
    }
    *(float4*)(CWo + CW_WU + d*32 + k0)     = make_float4(au[0],au[1],au[2],au[3]);
    *(float4*)(CWo + CW_WU + d*32 + k0 + 4) = make_float4(au[4],au[5],au[6],au[7]);
    *(float4*)(CWo + CW_WV + d*32 + k0)     = make_float4(av[0],av[1],av[2],av[3]);
    *(float4*)(CWo + CW_WV + d*32 + k0 + 4) = make_float4(av[4],av[5],av[6],av[7]);
  }
  if (t < 128) {
    const int kp = t >> 2, k0 = (t & 3) * 8;
    float a[8] = {0,0,0,0,0,0,0,0};
    for (int c = 0; c < 128; ++c) {
      const float vv = V_l[c*32 + kp];
      const float4 u0 = *(const float4*)(U + c*32 + k0);
      const float4 u1 = *(const float4*)(U + c*32 + k0 + 4);
      ACC8(a, vv, u0, u1);
    }
    *(float4*)(CWo + CW_VU + kp*32 + k0)     = make_float4(a[0],a[1],a[2],a[3]);
    *(float4*)(CWo + CW_VU + kp*32 + k0 + 4) = make_float4(a[4],a[5],a[6],a[7]);
  }
  if (t < 64) {
    float a = 0.f;
    for (int c = 0; c < 128; ++c) a += W_l[c*64 + t] * gw[c];
    CWo[CW_WG + t] = a;
  }
  if (t < 32) {
    float a1=0,a2=0,a3=0,a4=0,a5=0,a6=0;
    for (int c = 0; c < 128; ++c) {
      const float uv = U[c*32 + t], vv = V_l[c*32 + t], bc = b[c];
      a1 += vv*gw[c]; a2 += vv*gw[128+c];
      a3 += bc*uv;    a4 += uv;
      a5 += bc*vv;    a6 += vv;
    }
    CWo[CW_VGX+t]=a1; CWo[CW_VGH+t]=a2; CWo[CW_CBU+t]=a3; CWo[CW_CSU+t]=a4;
    CWo[CW_CBV+t]=a5; CWo[CW_CSV+t]=a6;
  }
  if (t == 0) {
    float bg=0.f, sg=0.f;
    for (int c = 0; c < 128; ++c) { bg += b[c]*gw[c]; sg += gw[c]; }
    CWo[CW_SC+0]=bg; CWo[CW_SC+1]=sg;
  }
}

// ---------------------------------------------------------------------------
// K1: stats via second moments (unchanged, proven). Per-block pair to PB.
// ---------------------------------------------------------------------------
__global__ __launch_bounds__(256,6)
void k_cov(const float* __restrict__ inp, const float* __restrict__ CW,
           double* __restrict__ PB, const int ntiles) {
  __shared__ float a_l[64*64];
  __shared__ float red[12];
  const int t = threadIdx.x;
  const int dg = t >> 4, eg = t & 15;
  const int d0 = dg*4, e0 = eg*4;
  float av1 = 0.f, av2 = 0.f, avb = 0.f;
  int nt = 0;
  for (int tile = blockIdx.x; tile < ntiles; tile += gridDim.x) {
    __syncthreads();
    const size_t r0 = (size_t)tile * 64;
    #pragma unroll
    for (int s = 0; s < 4; ++s) {
      int f = (t + 256*s) * 4;
      *(float4*)(a_l + f) = *(const float4*)(inp + r0*FIN + f);
    }
    __syncthreads();
    float S[4][4];
    #pragma unroll
    for (int i=0;i<4;i++)
      #pragma unroll
      for (int j=0;j<4;j++) S[i][j] = 0.f;
    float4 cs = make_float4(0.f,0.f,0.f,0.f);
    #pragma unroll 4
    for (int r = 0; r < 64; ++r) {
      const float4 ad = *(const float4*)(a_l + r*64 + d0);
      const float4 ae = *(const float4*)(a_l + r*64 + e0);
      S[0][0]+=ad.x*ae.x; S[0][1]+=ad.x*ae.y; S[0][2]+=ad.x*ae.z; S[0][3]+=ad.x*ae.w;
      S[1][0]+=ad.y*ae.x; S[1][1]+=ad.y*ae.y; S[1][2]+=ad.y*ae.z; S[1][3]+=ad.y*ae.w;
      S[2][0]+=ad.z*ae.x; S[2][1]+=ad.z*ae.y; S[2][2]+=ad.z*ae.z; S[2][3]+=ad.z*ae.w;
      S[3][0]+=ad.w*ae.x; S[3][1]+=ad.w*ae.y; S[3][2]+=ad.w*ae.z; S[3][3]+=ad.w*ae.w;
      cs.x += ad.x; cs.y += ad.y; cs.z += ad.z; cs.w += ad.w;
    }
    #pragma unroll
    for (int i = 0; i < 4; ++i) {
      const float4 g4 = *(const float4*)(CW + CW_G + (d0+i)*64 + e0);
      av2 += S[i][0]*g4.x + S[i][1]*g4.y + S[i][2]*g4.z + S[i][3]*g4.w;
    }
    if (eg == 0) {
      const float4 sw4 = *(const float4*)(CW + CW_SW + d0);
      const float4 wb4 = *(const float4*)(CW + CW_WB + d0);
      av1 += cs.x*sw4.x + cs.y*sw4.y + cs.z*sw4.z + cs.w*sw4.w;
      avb += cs.x*wb4.x + cs.y*wb4.y + cs.z*wb4.z + cs.w*wb4.w;
    }
    ++nt;
  }
  #pragma unroll
  for (int off = 32; off > 0; off >>= 1) {
    av2 += __shfl_xor(av2, off);
    av1 += __shfl_xor(av1, off);
    avb += __shfl_xor(avb, off);
  }
  const int w = t >> 6;
  if ((t & 63) == 0) { red[w*3] = av1; red[w*3+1] = av2; red[w*3+2] = avb; }
  __syncthreads();
  if (t == 0) {
    const float sb = CW[CW_SB], sb2 = CW[CW_SB+1];
    const double rowsB = 64.0 * (double)nt;
    const double s1 = (double)(red[0]+red[3]+red[6]+red[9]);
    const double s2 = (double)(red[1]+red[4]+red[7]+red[10]);
    const double sB = (double)(red[2]+red[5]+red[8]+red[11]);
    PB[(size_t)blockIdx.x*2 + 0] = s1 + rowsB*(double)sb;
    PB[(size_t)blockIdx.x*2 + 1] = s2 + 2.0*sB + rowsB*(double)sb2;
  }
}

// ---------------------------------------------------------------------------
// K1b: combine per-block double-pairs into ST[0..3]. One block.
// ---------------------------------------------------------------------------
__global__ __launch_bounds__(256)
void k_comb(const double* __restrict__ PBn, const double* __restrict__ PBf,
            double* __restrict__ ST) {
  __shared__ double red[8];
  const int t = threadIdx.x;
  double a = PBn[2*t] + PBn[2*(t+256)];
  double b = PBn[2*t+1] + PBn[2*(t+256)+1];
  #pragma unroll
  for (int off = 32; off > 0; off >>= 1) {
    a += __shfl_down(a, off);
    b += __shfl_down(b, off);
  }
  if ((t & 63) == 0) { red[(t>>6)*2] = a; red[(t>>6)*2+1] = b; }
  __syncthreads();
  if (t == 0) {
    ST[0] = red[0]+red[2]+red[4]+red[6];
    ST[1] = red[1]+red[3]+red[5]+red[7];
  }
  if (t < 64) {
    double c = (t < 20) ? PBf[2*t]   : 0.0;
    double d = (t < 20) ? PBf[2*t+1] : 0.0;
    #pragma unroll
    for (int off = 32; off > 0; off >>= 1) {
      c += __shfl_down(c, off);
      d += __shfl_down(d, off);
    }
    if (t == 0) { ST[2] = c; ST[3] = d; }
  }
}

// ---------------------------------------------------------------------------
// K1c: combine softmax partials (Pm/Ps 64-wide) into per-(b,j) M, 1/S.
// grid = 32 (one block per graph).
// ---------------------------------------------------------------------------
__global__ __launch_bounds__(256)
void k_comb2(const float* __restrict__ Pm, const float* __restrict__ Ps,
             float* __restrict__ MS) {
  __shared__ float Mq[160], Sq[160], Msh[40];
  const int t = threadIdx.x;
  const int b = blockIdx.x;
  const int j = t >> 2, q = t & 3;
  float pm[16];
  if (t < 160) {
    float m = 0.f;
    #pragma unroll
    for (int u = 0; u < 16; ++u) {
      pm[u] = Pm[(size_t)b*2560 + j*64 + q*16 + u];
      m = fmaxf(m, pm[u]);
    }
    Mq[t] = m;
  }
  __syncthreads();
  if (t < 40) Msh[t] = fmaxf(fmaxf(Mq[4*t], Mq[4*t+1]), fmaxf(Mq[4*t+2], Mq[4*t+3]));
  __syncthreads();
  if (t < 160) {
    const float M = Msh[j];
    float s = 0.f;
    #pragma unroll
    for (int u = 0; u < 16; ++u)
      s += Ps[(size_t)b*2560 + j*64 + q*16 + u] * __expf(pm[u] - M);
    Sq[t] = s;
  }
  __syncthreads();
  if (t < 40) {
    const float S = Sq[4*t] + Sq[4*t+1] + Sq[4*t+2] + Sq[4*t+3];
    MS[(size_t)b*80 + t] = Msh[t];
    MS[(size_t)b*80 + 40 + t] = 1.f/S;
  }
}

// ---------------------------------------------------------------------------
// irow4: 4 rows per thread. kq = t&3 (8-k slice), jh = (t>>2)&3 (10-j slice).
// p[i][jj] = full-k dot after xor1,2 (DPP) reduce. ypj stride 40.
// ---------------------------------------------------------------------------
__device__ __forceinline__ void irow4(const float* ypj, const int kq, const int jh,
                                      const float xp[4][8], float p[4][10]) {
  #pragma unroll
  for (int jj = 0; jj < 10; ++jj) {
    const int j = jh*10 + jj;
    const float4 y0 = *(const float4*)(ypj + j*40 + kq*8);
    const float4 y1 = *(const float4*)(ypj + j*40 + kq*8 + 4);
    #pragma unroll
    for (int i = 0; i < 4; ++i)
      p[i][jj] = dot8v(xp[i], y0, y1);
  }
  #pragma unroll
  for (int i = 0; i < 4; ++i)
    #pragma unroll
    for (int jj = 0; jj < 10; ++jj) {
      p[i][jj] += __shfl_xor(p[i][jj], 1);
      p[i][jj] += __shfl_xor(p[i][jj], 2);
    }
}

// ---------------------------------------------------------------------------
// partials_lds: softmax partials from p staged in LDS (stride 44). Proven.
// ---------------------------------------------------------------------------
__device__ __forceinline__ void partials_lds(const float* p_l, const int t,
    float* sredm, float* sreds, float* redm,
    float* __restrict__ PmB, float* __restrict__ PsB) {
  const int r2 = t >> 2, kq = t & 3;
  const int w = t >> 6, tl = t & 63;
  float ev[10];
  #pragma unroll
  for (int m = 0; m < 10; ++m) ev[m] = p_l[r2*44 + 4*m + kq];
  float mv[10];
  #pragma unroll
  for (int m = 0; m < 10; ++m) {
    mv[m] = ev[m];
    mv[m] = fmaxf(mv[m], __shfl_xor(mv[m], 4));
    mv[m] = fmaxf(mv[m], __shfl_xor(mv[m], 8));
    mv[m] = fmaxf(mv[m], __shfl_xor(mv[m], 16));
    mv[m] = fmaxf(mv[m], __shfl_xor(mv[m], 32));
  }
  if (tl < 4) {
    #pragma unroll
    for (int m = 0; m < 10; ++m) sredm[w*40 + 4*m + kq] = mv[m];
  }
  __syncthreads();
  if (t < 40)
    redm[t] = fmaxf(fmaxf(sredm[t], sredm[40+t]), fmaxf(sredm[80+t], sredm[120+t]));
  __syncthreads();
  float es[10];
  #pragma unroll
  for (int m = 0; m < 10; ++m) {
    const float M = redm[4*m + kq];
    es[m] = __expf(ev[m]-M);
    es[m] += __shfl_xor(es[m], 4);
    es[m] += __shfl_xor(es[m], 8);
    es[m] += __shfl_xor(es[m], 16);
    es[m] += __shfl_xor(es[m], 32);
  }
  if (tl < 4) {
    #pragma unroll
    for (int m = 0; m < 10; ++m) sreds[w*40 + 4*m + kq] = es[m];
  }
  __syncthreads();
  if (t < 40) {
    PmB[(size_t)t*64] = redm[t];
    PsB[(size_t)t*64] = sreds[t]+sreds[40+t]+sreds[80+t]+sreds[120+t];
  }
}

// ---------------------------------------------------------------------------
// K2: y_p directly from fe (unchanged, proven).
// ---------------------------------------------------------------------------
__global__ __launch_bounds__(256,4)
void k_yp2(const float* __restrict__ fe, const float* __restrict__ CW,
           const float* __restrict__ q, const double* __restrict__ ST,
           float* __restrict__ yp) {
  __shared__ float in_t[64*64];
  __shared__ float Wl[64*32];
  const int t = threadIdx.x;
  const int r0 = blockIdx.x * 64;
  #pragma unroll
  for (int s = 0; s < 4; ++s) {
    int f = (t + 256*s) * 4;
    int r = f >> 6, d = f & 63;
    float4 v = *(const float4*)(fe + (size_t)r0*FIN + f);
    *(float4*)(in_t + r*64 + (d ^ ((r & 7) * 8))) = v;
  }
  #pragma unroll
  for (int s = 0; s < 2; ++s) {
    int f = (t + 256*s) * 4;
    *(float4*)(Wl + f) = *(const float4*)(CW + CW_WV + f);
  }
  __syncthreads();
  const double cy = (double)YROWS * (double)C;
  const double myd = ST[2]/cy, vy = ST[3]/cy - myd*myd;
  const float ry = (float)(1.0/sqrt(vy + (double)EPS));
  const float mr = (float)myd * ry;
  const int r2 = t >> 2, kq = t & 3;
  const int swz = (r2 & 7) * 8;
  float acc[8] = {0,0,0,0,0,0,0,0};
  #pragma unroll
  for (int dc = 0; dc < 16; ++dc) {
    const int d = dc*4;
    const float4 a = *(const float4*)(in_t + r2*64 + (d ^ swz));
    { const float4 w0 = *(const float4*)(Wl + (d+0)*32 + kq*8);
      const float4 w1 = *(const float4*)(Wl + (d+0)*32 + kq*8 + 4); ACC8(acc, a.x, w0, w1); }
    { const float4 w0 = *(const float4*)(Wl + (d+1)*32 + kq*8);
      const float4 w1 = *(const float4*)(Wl + (d+1)*32 + kq*8 + 4); ACC8(acc, a.y, w0, w1); }
    { const float4 w0 = *(const float4*)(Wl + (d+2)*32 + kq*8);
      const float4 w1 = *(const float4*)(Wl + (d+2)*32 + kq*8 + 4); ACC8(acc, a.z, w0, w1); }
    { const float4 w0 = *(const float4*)(Wl + (d+3)*32 + kq*8);
      const float4 w1 = *(const float4*)(Wl + (d+3)*32 + kq*8 + 4); ACC8(acc, a.w, w0, w1); }
  }
  #pragma unroll
  for (int i = 0; i < 8; ++i) {
    const int k = kq*8 + i;
    const float typ = ry*(acc[i] + CW[CW_CBV+k]) - mr*CW[CW_CSV+k];
    float v = fmaxf(typ, 0.f);
    acc[i] = fmaxf(q[k]*v, 0.f);
  }
  *(float4*)(yp + (size_t)(r0+r2)*KK + kq*8)     = make_float4(acc[0],acc[1],acc[2],acc[3]);
  *(float4*)(yp + (size_t)(r0+r2)*KK + kq*8 + 4) = make_float4(acc[4],acc[5],acc[6],acc[7]);
}

// ---------------------------------------------------------------------------
// K3: layer-0, 4-row register-blocked (unchanged from round-6: passed, fast).
// ---------------------------------------------------------------------------
__global__ __launch_bounds__(256,4)
void k_I0b(const float* __restrict__ nf, const float* __restrict__ CW,
           const double* __restrict__ ST, const float* __restrict__ yp,
           float* __restrict__ XU, float* __restrict__ GX,
           float* __restrict__ Pm, float* __restrict__ Ps) {
  __shared__ __align__(16) float in_t[64*68];   // overlaid by p_l (64*44) later
  __shared__ __align__(16) float Wl[64*36];     // row d -> (d&15)*4 + (d>>4)
  __shared__ __align__(16) float ypj[40*40];
  __shared__ __align__(16) float wgl[64];
  __shared__ float sredm[160], sreds[160], redm[40];
  float* p_l = in_t;
  const int t = threadIdx.x;
  const int bid = blockIdx.x;
  const int b = bid >> 6, blk = bid & 63;
  const size_t rowbase = (size_t)b*NPG + (size_t)blk*64;
  #pragma unroll
  for (int s = 0; s < 4; ++s) {
    int f = (t + 256*s) * 4;
    int r = f >> 6, d = f & 63;
    *(float4*)(in_t + r*68 + d) = *(const float4*)(nf + rowbase*FIN + f);
  }
  #pragma unroll
  for (int s = 0; s < 2; ++s) {
    int idx = t + 256*s;
    int d = idx >> 3, kc = idx & 7;
    *(float4*)(Wl + ((d&15)*4 + (d>>4))*36 + kc*4) = *(const float4*)(CW + CW_WU + idx*4);
  }
  for (int f4v = t; f4v < 320; f4v += 256) {
    int j = f4v >> 3, kc = f4v & 7;
    *(float4*)(ypj + j*40 + kc*4) = *(const float4*)(yp + (size_t)b*(JJ*KK) + f4v*4);
  }
  if (t < 64) wgl[t] = CW[CW_WG + t];
  __syncthreads();
  const double cx = (double)NTOT * (double)C;
  const double mx = ST[0]/cx, vx = ST[1]/cx - mx*mx;
  const float rx = (float)(1.0/sqrt(vx + (double)EPS));
  const float mr = (float)mx * rx;
  const int kq = t & 3, X = (t >> 2) & 3, rr = t >> 4;
  float acc[4][8];
  #pragma unroll
  for (int i=0;i<4;i++)
    #pragma unroll
    for (int u=0;u<8;u++) acc[i][u] = 0.f;
  #pragma unroll
  for (int dd = 0; dd < 4; ++dd) {
    float4 a4[4];
    #pragma unroll
    for (int i = 0; i < 4; ++i)
      a4[i] = *(const float4*)(in_t + (rr+16*i)*68 + X*16 + dd*4);
    #pragma unroll
    for (int qd = 0; qd < 4; ++qd) {
      const int lrow = (dd*4 + qd)*4 + X;
      const float4 w0 = *(const float4*)(Wl + lrow*36 + kq*8);
      const float4 w1 = *(const float4*)(Wl + lrow*36 + kq*8 + 4);
      #pragma unroll
      for (int i = 0; i < 4; ++i) {
        const float av = (qd==0)? a4[i].x : (qd==1)? a4[i].y : (qd==2)? a4[i].z : a4[i].w;
        ACC8(acc[i], av, w0, w1);
      }
    }
  }
  // X-reduce (full 64-d sum)
  #pragma unroll
  for (int i = 0; i < 4; ++i)
    #pragma unroll
    for (int u = 0; u < 8; ++u) {
      acc[i][u] += __shfl_xor(acc[i][u], 4);
      acc[i][u] += __shfl_xor(acc[i][u], 8);
    }
  // gx: d-slice (X*16 + kq*4), reduce over 16 lanes
  float gp[4];
  #pragma unroll
  for (int i = 0; i < 4; ++i) {
    const float4 a = *(const float4*)(in_t + (rr+16*i)*68 + X*16 + kq*4);
    const float4 w = *(const float4*)(wgl + X*16 + kq*4);
    gp[i] = dot4(a, w);
    gp[i] += __shfl_xor(gp[i], 1);
    gp[i] += __shfl_xor(gp[i], 2);
    gp[i] += __shfl_xor(gp[i], 4);
    gp[i] += __shfl_xor(gp[i], 8);
  }
  const float4 cb0 = *(const float4*)(CW + CW_CBU + kq*8);
  const float4 cb1 = *(const float4*)(CW + CW_CBU + kq*8 + 4);
  const float4 cu0 = *(const float4*)(CW + CW_CSU + kq*8);
  const float4 cu1 = *(const float4*)(CW + CW_CSU + kq*8 + 4);
  float xp[4][8];
  #pragma unroll
  for (int i = 0; i < 4; ++i) {
    acc[i][0] = rx*(acc[i][0] + cb0.x) - mr*cu0.x;
    acc[i][1] = rx*(acc[i][1] + cb0.y) - mr*cu0.y;
    acc[i][2] = rx*(acc[i][2] + cb0.z) - mr*cu0.z;
    acc[i][3] = rx*(acc[i][3] + cb0.w) - mr*cu0.w;
    acc[i][4] = rx*(acc[i][4] + cb1.x) - mr*cu1.x;
    acc[i][5] = rx*(acc[i][5] + cb1.y) - mr*cu1.y;
    acc[i][6] = rx*(acc[i][6] + cb1.z) - mr*cu1.z;
    acc[i][7] = rx*(acc[i][7] + cb1.w) - mr*cu1.w;
    #pragma unroll
    for (int u = 0; u < 8; ++u) xp[i][u] = fmaxf(acc[i][u], 0.f);
  }
  if (X == 0) {
    const float bG = CW[CW_SC], sG = CW[CW_SC+1];
    #pragma unroll
    for (int i = 0; i < 4; ++i) {
      const size_t row = rowbase + rr + 16*i;
      *(float4*)(XU + row*KK + kq*8)     = make_float4(acc[i][0],acc[i][1],acc[i][2],acc[i][3]);
      *(float4*)(XU + row*KK + kq*8 + 4) = make_float4(acc[i][4],acc[i][5],acc[i][6],acc[i][7]);
      if (kq == 0) GX[row] = rx*(gp[i] + bG) - mr*sG;
    }
  }
  float p[4][10];
  irow4(ypj, kq, X, xp, p);
  __syncthreads();                       // all in_t reads done; overlay p_l
  if (kq == 0) {
    #pragma unroll
    for (int i = 0; i < 4; ++i)
      #pragma unroll
      for (int u = 0; u < 5; ++u)
        *(float2*)(p_l + (rr+16*i)*44 + X*10 + 2*u) = make_float2(p[i][2*u], p[i][2*u+1]);
  }
  __syncthreads();
  partials_lds(p_l, t, sredm, sreds, redm,
               Pm + (size_t)b*2560 + blk, Ps + (size_t)b*2560 + blk);
}

// ---------------------------------------------------------------------------
// K4: fused layer update, 4-row blocked, FUSED STREAMING (spill fix):
// per jj: load y once -> p4 (dot + xor1/2) -> e -> accumulate hp with SAME y.
// No p[4][10] array; peak regs ~90. Then h reduce (xor4/8) -> h_l -> phase C
// -> streamed final-I (squared-sum or scalar p_l stores) -> partials/out.
// ---------------------------------------------------------------------------
template<int FINAL>
__global__ __launch_bounds__(256,2)
void k_fused4(float* __restrict__ XU, float* __restrict__ GX,
              const float* __restrict__ yp, const float* __restrict__ CW,
              const float* __restrict__ gb, const float* __restrict__ MS,
              float* __restrict__ PmOut, float* __restrict__ PsOut,
              float* __restrict__ outp) {
  __shared__ __align__(16) float ypj[40*40];
  __shared__ __align__(16) float xp_l[64*36];
  __shared__ __align__(16) float BUF[3456];   // h_l[64*36] | VU_l[32*36]; later p_l[64*44]
  __shared__ __align__(16) float vg_l[64];    // vgx[0:32], vgh[32:64]
  __shared__ float M_l[40], Si_l[40];
  __shared__ float sredm[160], sreds[160], redm[40];
  float* h_l  = BUF;
  float* VU_l = BUF + 2304;
  float* p_l  = BUF;
  const int t = threadIdx.x;
  const int bid = blockIdx.x;
  const int b = bid >> 6, blk = bid & 63;
  const size_t rowbase = (size_t)b*NPG + (size_t)blk*64;
  for (int f4v = t; f4v < 320; f4v += 256) {
    int j = f4v >> 3, kc = f4v & 7;
    *(float4*)(ypj + j*40 + kc*4) = *(const float4*)(yp + (size_t)b*(JJ*KK) + f4v*4);
  }
  { // VU (original orientation [kp][k]) stride 36
    const int d = t >> 3, kc = t & 7;
    *(float4*)(VU_l + d*36 + kc*4) = *(const float4*)(CW + CW_VU + t*4);
  }
  if (t < 32) vg_l[t] = CW[CW_VGX + t];
  else if (t < 64) vg_l[t] = CW[CW_VGH + t - 32];
  if (t < 40) { M_l[t] = MS[(size_t)b*80 + t]; Si_l[t] = MS[(size_t)b*80 + 40 + t]; }
  __syncthreads();
  const int kq = t & 3, jh = (t >> 2) & 3, rr = t >> 4;
  // load state, xp (relu'd)
  float xp[4][8];
  #pragma unroll
  for (int i = 0; i < 4; ++i) {
    const size_t row = rowbase + rr + 16*i;
    const float4 x0 = *(const float4*)(XU + row*KK + kq*8);
    const float4 x1 = *(const float4*)(XU + row*KK + kq*8 + 4);
    xp[i][0]=fmaxf(x0.x,0.f); xp[i][1]=fmaxf(x0.y,0.f);
    xp[i][2]=fmaxf(x0.z,0.f); xp[i][3]=fmaxf(x0.w,0.f);
    xp[i][4]=fmaxf(x1.x,0.f); xp[i][5]=fmaxf(x1.y,0.f);
    xp[i][6]=fmaxf(x1.z,0.f); xp[i][7]=fmaxf(x1.w,0.f);
  }
  // FUSED phase A+B: per jj -> p4 -> e -> hp, y read once
  float hp[4][8];
  #pragma unroll
  for (int i=0;i<4;i++)
    #pragma unroll
    for (int u=0;u<8;u++) hp[i][u] = 0.f;
  #pragma unroll
  for (int jj = 0; jj < 10; ++jj) {
    const int j = jh*10 + jj;
    const float4 y0 = *(const float4*)(ypj + j*40 + kq*8);
    const float4 y1 = *(const float4*)(ypj + j*40 + kq*8 + 4);
    float p4[4];
    #pragma unroll
    for (int i = 0; i < 4; ++i) p4[i] = dot8v(xp[i], y0, y1);
    #pragma unroll
    for (int i = 0; i < 4; ++i) {
      p4[i] += __shfl_xor(p4[i], 1);
      p4[i] += __shfl_xor(p4[i], 2);
    }
    const float Mj = M_l[j], Sj = Si_l[j];
    #pragma unroll
    for (int i = 0; i < 4; ++i) {
      const float e = __expf(p4[i] - Mj) * Sj;
      ACC8(hp[i], e, y0, y1);
    }
  }
  // jh-reduce -> full j sum
  #pragma unroll
  for (int i = 0; i < 4; ++i)
    #pragma unroll
    for (int u = 0; u < 8; ++u) {
      hp[i][u] += __shfl_xor(hp[i][u], 4);
      hp[i][u] += __shfl_xor(hp[i][u], 8);
    }
  if (jh == 0) {
    #pragma unroll
    for (int i = 0; i < 4; ++i) {
      const int rl = rr + 16*i;
      *(float4*)(h_l + rl*36 + kq*8) =
        make_float4(fmaxf(hp[i][0],0.f), fmaxf(hp[i][1],0.f),
                    fmaxf(hp[i][2],0.f), fmaxf(hp[i][3],0.f));
      *(float4*)(h_l + rl*36 + kq*8 + 4) =
        make_float4(fmaxf(hp[i][4],0.f), fmaxf(hp[i][5],0.f),
                    fmaxf(hp[i][6],0.f), fmaxf(hp[i][7],0.f));
    }
  }
  __syncthreads();
  // phase C: 2 output k per lane, full kp contraction, gate + blend
  {
    const int kk2 = t & 15, rr2 = t >> 4;
    float hu0[4] = {0,0,0,0}, hu1[4] = {0,0,0,0};
    float g2[4] = {0,0,0,0}, gxp[4] = {0,0,0,0};
    #pragma unroll
    for (int c8 = 0; c8 < 8; ++c8) {
      const float4 vgx4 = *(const float4*)(vg_l + c8*4);
      const float4 vgh4 = *(const float4*)(vg_l + 32 + c8*4);
      float2 vu[4];
      #pragma unroll
      for (int qd = 0; qd < 4; ++qd)
        vu[qd] = *(const float2*)(VU_l + (c8*4+qd)*36 + kk2*2);
      #pragma unroll
      for (int i = 0; i < 4; ++i) {
        const float4 h4 = *(const float4*)(h_l + (rr2+16*i)*36 + c8*4);
        g2[i]  += dot4(h4, vgh4);
        gxp[i] += dot4(h4, vgx4);
        hu0[i] += h4.x*vu[0].x + h4.y*vu[1].x + h4.z*vu[2].x + h4.w*vu[3].x;
        hu1[i] += h4.x*vu[0].y + h4.y*vu[1].y + h4.z*vu[2].y + h4.w*vu[3].y;
      }
    }
    const float gbv = gb[0];
    #pragma unroll
    for (int i = 0; i < 4; ++i) {
      const size_t row = rowbase + rr2 + 16*i;
      const float gx = GX[row];
      const float2 xu2 = *(const float2*)(XU + row*KK + kk2*2);
      const float z = sigm(gx + g2[i] + gbv);
      const float nx0 = (1.f-z)*xu2.x + z*hu0[i];
      const float nx1 = (1.f-z)*xu2.y + z*hu1[i];
      if (!FINAL) {
        *(float2*)(XU + row*KK + kk2*2) = make_float2(nx0, nx1);
        if (kk2 == 0) GX[row] = (1.f-z)*gx + z*gxp[i];
      }
      *(float2*)(xp_l + (rr2+16*i)*36 + kk2*2) = make_float2(fmaxf(nx0,0.f), fmaxf(nx1,0.f));
    }
  }
  __syncthreads();
  // reload updated xp
  #pragma unroll
  for (int i = 0; i < 4; ++i) {
    const int rl = rr + 16*i;
    const float4 x0 = *(const float4*)(xp_l + rl*36 + kq*8);
    const float4 x1 = *(const float4*)(xp_l + rl*36 + kq*8 + 4);
    xp[i][0]=x0.x; xp[i][1]=x0.y; xp[i][2]=x0.z; xp[i][3]=x0.w;
    xp[i][4]=x1.x; xp[i][5]=x1.y; xp[i][6]=x1.z; xp[i][7]=x1.w;
  }
  // streamed final-I
  if (FINAL) {
    float s[4] = {0.f,0.f,0.f,0.f};
    #pragma unroll
    for (int jj = 0; jj < 10; ++jj) {
      const int j = jh*10 + jj;
      const float4 y0 = *(const float4*)(ypj + j*40 + kq*8);
      const float4 y1 = *(const float4*)(ypj + j*40 + kq*8 + 4);
      float p4[4];
      #pragma unroll
      for (int i = 0; i < 4; ++i) p4[i] = dot8v(xp[i], y0, y1);
      #pragma unroll
      for (int i = 0; i < 4; ++i) {
        p4[i] += __shfl_xor(p4[i], 1);
        p4[i] += __shfl_xor(p4[i], 2);
        s[i] += p4[i]*p4[i];
      }
    }
    #pragma unroll
    for (int i = 0; i < 4; ++i) {
      s[i] += __shfl_xor(s[i], 4);
      s[i] += __shfl_xor(s[i], 8);
    }
    if ((t & 15) == 0) {
      #pragma unroll
      for (int i = 0; i < 4; ++i)
        outp[rowbase + rr + 16*i] = sigm(s[i]);
    }
    return;
  }
  #pragma unroll
  for (int jj = 0; jj < 10; ++jj) {
    const int j = jh*10 + jj;
    const float4 y0 = *(const float4*)(ypj + j*40 + kq*8);
    const float4 y1 = *(const float4*)(ypj + j*40 + kq*8 + 4);
    float p4[4];
    #pragma unroll
    for (int i = 0; i < 4; ++i) p4[i] = dot8v(xp[i], y0, y1);
    #pragma unroll
    for (int i = 0; i < 4; ++i) {
      p4[i] += __shfl_xor(p4[i], 1);
      p4[i] += __shfl_xor(p4[i], 2);
    }
    if (kq == 0) {
      #pragma unroll
      for (int i = 0; i < 4; ++i)
        p_l[(rr+16*i)*44 + j] = p4[i];
    }
  }
  __syncthreads();
  partials_lds(p_l, t, sredm, sreds, redm,
               PmOut + (size_t)b*2560 + blk, PsOut + (size_t)b*2560 + blk);
}

extern "C" void kernel_launch(void* const* d_in, const int* in_sizes, int n_in,
                              void* d_out, int out_size, void* d_ws, size_t ws_size,
                              hipStream_t stream) {
  const float* nf  = (const float*)d_in[0];
  const float* fe  = (const float*)d_in[1];
  const float* W   = (const float*)d_in[2];
  const float* bin = (const float*)d_in[3];
  const float* U   = (const float*)d_in[4];
  const float* V   = (const float*)d_in[5];
  const float* q   = (const float*)d_in[6];
  const float* gw  = (const float*)d_in[7];
  const float* gb  = (const float*)d_in[8];
  float* out = (float*)d_out;
  float* wf  = (float*)d_ws;

  float* XU  = wf + XU_OFF;
  float* GX  = wf + GX_OFF;
  float* YP  = wf + YP_OFF;
  float* PMa = wf + PMA_OFF;
  float* PSa = wf + PSA_OFF;
  float* PMb = wf + PMB_OFF;
  float* PSb = wf + PSB_OFF;
  float* CWp = wf + CWS_OFF;
  float* MSb = wf + MS_OFF;
  double* PBn = (double*)(wf + PBN_OFF);
  double* PBf = (double*)(wf + PBF_OFF);
  double* ST  = (double*)(wf + ST_OFF);

  k_pre<<<2, 256, 0, stream>>>(W, bin, U, V, gw, CWp);
  k_cov<<<512, 256, 0, stream>>>(nf, CWp, PBn, NTOT/64);
  k_cov<<<20, 256, 0, stream>>>(fe, CWp, PBf, YROWS/64);
  k_comb<<<1, 256, 0, stream>>>(PBn, PBf, ST);
  k_yp2<<<YROWS/64, 256, 0, stream>>>(fe, CWp, q, ST, YP);
  k_I0b<<<NTOT/64, 256, 0, stream>>>(nf, CWp, ST, YP, XU, GX, PMa, PSa);
  k_comb2<<<32, 256, 0, stream>>>(PMa, PSa, MSb);
  k_fused4<0><<<NTOT/64, 256, 0, stream>>>(XU, GX, YP, CWp, gb, MSb, PMb, PSb, nullptr);
  k_comb2<<<32, 256, 0, stream>>>(PMb, PSb, MSb);
  k_fused4<1><<<NTOT/64, 256, 0, stream>>>(XU, GX, YP, CWp, gb, MSb, nullptr, nullptr, out);
}